// Round 8
// baseline (225.411 us; speedup 1.0000x reference)
//
#include <hip/hip_runtime.h>
#include <math.h>

#define NQ   8192
#define NK   4096
#define DIM  768
#define LL   8
#define CCAP 64

typedef _Float16 f16;
typedef __attribute__((ext_vector_type(4))) _Float16 f16x4;
typedef __attribute__((ext_vector_type(8))) _Float16 f16x8;
typedef __attribute__((ext_vector_type(4))) float f32x4;
typedef unsigned long long u64;

__device__ inline unsigned ordf(float f) {           // monotonic f32->u32
    unsigned u = __float_as_uint(f);
    return (u & 0x80000000u) ? ~u : (u | 0x80000000u);
}
__device__ inline float iord(unsigned u) {           // inverse of ordf
    unsigned b = (u & 0x80000000u) ? (u & 0x7fffffffu) : ~u;
    return __uint_as_float(b);
}

__device__ __forceinline__ void gload16(const void* g, void* l) {
    __builtin_amdgcn_global_load_lds((const __attribute__((address_space(1))) void*)g,
                                     (__attribute__((address_space(3))) void*)l, 16, 0, 0);
}

// ---------- prep: f16 conversion of x (rows 0..8191) and e_k (rows 8192..12287) ----------
__global__ __launch_bounds__(256) void prep(const float* __restrict__ xq,
                                            const float* __restrict__ ek,
                                            f16* __restrict__ Xh,
                                            f16* __restrict__ Eh,
                                            float* __restrict__ margin,
                                            float* __restrict__ inv_n) {
    const int wid = threadIdx.x >> 6, lane = threadIdx.x & 63;
    const int row = blockIdx.x * 4 + wid;              // 0..12287
    const bool isX = row < NQ;
    const f32x4* src = (const f32x4*)(isX ? xq + (size_t)row * DIM
                                          : ek + (size_t)(row - NQ) * DIM);
    f16x4* dst = (f16x4*)(isX ? Xh + (size_t)row * DIM : Eh + (size_t)(row - NQ) * DIM);
    float s2 = 0.f;
#pragma unroll
    for (int j = 0; j < 3; ++j) {
        const f32x4 v = src[j * 64 + lane];
        s2 = fmaf(v.x, v.x, fmaf(v.y, v.y, fmaf(v.z, v.z, fmaf(v.w, v.w, s2))));
        dst[j * 64 + lane] = (f16x4){(f16)v.x, (f16)v.y, (f16)v.z, (f16)v.w};
    }
#pragma unroll
    for (int off = 32; off; off >>= 1) s2 += __shfl_xor(s2, off);
    if (lane == 0) {
        if (isX) margin[row] = sqrtf(s2) * 1.5e-4f + 2e-3f;   // ~13 sigma of fp16 noise
        else     inv_n[row - NQ] = 1.0f / fmaxf(sqrtf(s2), 1e-12f);
    }
}

// ---------- 256x256 fp16 MFMA GEMM with fused candidate emit ----------
// 8 waves (2M x 4N), wave tile 128x64, BK=64, m97 2-barrier staging.
__global__ __launch_bounds__(512, 2) void gemm256(const f16* __restrict__ Xh,
                                                  const f16* __restrict__ Eh,
                                                  const float* __restrict__ inv_n,
                                                  const float* __restrict__ marg,
                                                  int* __restrict__ cnt,
                                                  u64* __restrict__ cand) {
    __shared__ f16 A[256 * 64], B[256 * 64];
    __shared__ float rmax[4][256];
    const int t = threadIdx.x, lane = t & 63, wid = t >> 6;
    const int wm = wid & 1, wn = wid >> 1;
    const int qbase = blockIdx.x * 256, kbase = blockIdx.y * 256;

    f32x4 acc[8][4];
#pragma unroll
    for (int mi = 0; mi < 8; ++mi)
#pragma unroll
        for (int ni = 0; ni < 4; ++ni) acc[mi][ni] = (f32x4){0.f, 0.f, 0.f, 0.f};

    // staging: pass p stages rows p*64 + t/8, col chunk (t%8)*8 (16 B / thread)
    const f16* gA = Xh + (size_t)(qbase + (t >> 3)) * DIM + (t & 7) * 8;
    const f16* gB = Eh + (size_t)(kbase + (t >> 3)) * DIM + (t & 7) * 8;
    f16* lA = &A[t * 8];
    f16* lB = &B[t * 8];

    for (int kk = 0; kk < DIM; kk += 64) {
        __syncthreads();
#pragma unroll
        for (int p = 0; p < 4; ++p) {
            gload16(gA + (size_t)(p * 64) * DIM + kk, lA + p * 4096);
            gload16(gB + (size_t)(p * 64) * DIM + kk, lB + p * 4096);
        }
        __syncthreads();

#pragma unroll
        for (int kk2 = 0; kk2 < 2; ++kk2) {
            const int ko = kk2 * 32 + (lane >> 4) * 8;
            f16x8 ah[8], bh[4];
#pragma unroll
            for (int mi = 0; mi < 8; ++mi)
                ah[mi] = *(const f16x8*)&A[(wm * 128 + mi * 16 + (lane & 15)) * 64 + ko];
#pragma unroll
            for (int ni = 0; ni < 4; ++ni)
                bh[ni] = *(const f16x8*)&B[(wn * 64 + ni * 16 + (lane & 15)) * 64 + ko];
#pragma unroll
            for (int mi = 0; mi < 8; ++mi)
#pragma unroll
                for (int ni = 0; ni < 4; ++ni)
                    acc[mi][ni] = __builtin_amdgcn_mfma_f32_16x16x32_f16(ah[mi], bh[ni], acc[mi][ni], 0, 0, 0);
        }
    }

    // ---- fused epilogue: per-row block max -> margin test -> emit candidates ----
    // C/D layout (verified): col = lane&15, row = (lane>>4)*4 + reg
    const int rg = lane >> 4, cid = lane & 15;
    float invv[4];
    int key[4];
#pragma unroll
    for (int ni = 0; ni < 4; ++ni) {
        key[ni] = kbase + wn * 64 + ni * 16 + cid;
        invv[ni] = inv_n[key[ni]];
    }

    // pass 1: per-row max over this block's 256 cols
#pragma unroll
    for (int mi = 0; mi < 8; ++mi)
#pragma unroll
        for (int rj = 0; rj < 4; ++rj) {
            float lm = acc[mi][0][rj] * invv[0];
            lm = fmaxf(lm, acc[mi][1][rj] * invv[1]);
            lm = fmaxf(lm, acc[mi][2][rj] * invv[2]);
            lm = fmaxf(lm, acc[mi][3][rj] * invv[3]);
#pragma unroll
            for (int off = 1; off < 16; off <<= 1) lm = fmaxf(lm, __shfl_xor(lm, off));
            if (cid == 0) rmax[wn][wm * 128 + mi * 16 + rg * 4 + rj] = lm;
        }
    __syncthreads();

    // pass 2: threshold + emit
#pragma unroll
    for (int mi = 0; mi < 8; ++mi)
#pragma unroll
        for (int rj = 0; rj < 4; ++rj) {
            const int rl = wm * 128 + mi * 16 + rg * 4 + rj;
            const float bm = fmaxf(fmaxf(rmax[0][rl], rmax[1][rl]),
                                   fmaxf(rmax[2][rl], rmax[3][rl]));
            const int row = qbase + rl;
            const float thr = bm - marg[row];
#pragma unroll
            for (int ni = 0; ni < 4; ++ni) {
                const float v = acc[mi][ni][rj] * invv[ni];
                if (v >= thr) {
                    const int idx = atomicAdd(&cnt[row], 1);
                    if (idx < CCAP)
                        cand[(size_t)row * CCAP + idx] =
                            ((u64)ordf(v) << 32) | (unsigned)key[ni];
                }
            }
        }
}

// ---------- resolve: per-row candidate max, margin, exact f32 rescore, argmax ----------
__global__ __launch_bounds__(256) void resolve(const int* __restrict__ cnt,
                                               const u64* __restrict__ cand,
                                               const float* __restrict__ marg,
                                               const float* __restrict__ inv_n,
                                               const float* __restrict__ xq,
                                               const float* __restrict__ ek,
                                               int* __restrict__ bestk) {
    const int wid = threadIdx.x >> 6, lane = threadIdx.x & 63;
    const int r = blockIdx.x * 4 + wid;               // one wave per query row
    int n = cnt[r];
    n = n < CCAP ? n : CCAP;
    const u64* cr = cand + (size_t)r * CCAP;

    u64 cm = 0;
    for (int e = lane; e < n; e += 64) { const u64 c = cr[e]; cm = cm > c ? cm : c; }
#pragma unroll
    for (int off = 32; off; off >>= 1) {
        const u64 o = __shfl_xor(cm, off);
        cm = cm > o ? cm : o;
    }
    const float thr = iord((unsigned)(cm >> 32)) - marg[r];

    const f32x4* xr = (const f32x4*)(xq + (size_t)r * DIM);
    const f32x4 xa = xr[lane * 3], xb = xr[lane * 3 + 1], xc = xr[lane * 3 + 2];

    u64 best = 0;
    for (int e = 0; e < n; ++e) {
        const u64 c = cr[e];
        if (iord((unsigned)(c >> 32)) < thr) continue;
        const int k = (int)(unsigned)(c & 0xffffffffu);
        const f32x4* er = (const f32x4*)(ek + (size_t)k * DIM);
        const f32x4 ea = er[lane * 3], eb = er[lane * 3 + 1], ec = er[lane * 3 + 2];
        float s = xa.x * ea.x;
        s = fmaf(xa.y, ea.y, s); s = fmaf(xa.z, ea.z, s); s = fmaf(xa.w, ea.w, s);
        s = fmaf(xb.x, eb.x, s); s = fmaf(xb.y, eb.y, s); s = fmaf(xb.z, eb.z, s);
        s = fmaf(xb.w, eb.w, s); s = fmaf(xc.x, ec.x, s); s = fmaf(xc.y, ec.y, s);
        s = fmaf(xc.z, ec.z, s); s = fmaf(xc.w, ec.w, s);
#pragma unroll
        for (int off = 32; off; off >>= 1) s += __shfl_xor(s, off);
        const float ve = s * inv_n[k];
        const u64 p64 = ((u64)ordf(ve) << 32) | (unsigned)(NK - 1 - k);
        best = best > p64 ? best : p64;
    }
    if (lane == 0) bestk[r] = NK - 1 - (int)(unsigned)(best & 0xffffffffu);
}

// ---------- flat gather with nontemporal output stores ----------
__global__ __launch_bounds__(256) void gather_flat(const int* __restrict__ bestk,
                                                   const float* __restrict__ e_p,
                                                   const float* __restrict__ x_block,
                                                   f32x4* __restrict__ o) {
    const int EK4 = NQ * 4 * (DIM / 4);          // 6,291,456
    const int XB4 = 2 * EK4;                     // 12,582,912
    const int TOT = XB4 + NQ * (DIM / 4);        // 14,155,776
    const int stride = gridDim.x * 256;
    const f32x4* ep4 = (const f32x4*)e_p;
    const f32x4* xb4 = (const f32x4*)x_block;
#pragma unroll 1
    for (int f = blockIdx.x * 256 + threadIdx.x; f < TOT; f += stride) {
        f32x4 v;
        if (f < XB4) {
            const int g = (f >= EK4) ? f - EK4 : f;
            const int b = g / (4 * DIM / 4);
            const int k = bestk[b];
            const int off = (f >= EK4) ? 4 * (DIM / 4) : 0;
            v = ep4[(size_t)k * (LL * DIM / 4) + off + (g - b * 768)];
        } else {
            v = __builtin_nontemporal_load(&xb4[f - XB4]);
        }
        __builtin_nontemporal_store(v, &o[f]);
    }
}

// ---------- launch ----------
extern "C" void kernel_launch(void* const* d_in, const int* in_sizes, int n_in,
                              void* d_out, int out_size, void* d_ws, size_t ws_size,
                              hipStream_t stream) {
    const float* x_querry = (const float*)d_in[0];
    const float* x_block  = (const float*)d_in[1];
    const float* e_k      = (const float*)d_in[2];
    const float* e_p      = (const float*)d_in[3];

    // scratch carved from d_out (226.5 MB), fully consumed before gather overwrites it
    char* base = (char*)d_out;
    f16*   Xh   = (f16*)(base);                   // 12,582,912 B
    f16*   Eh   = (f16*)(base + 12582912);        //  6,291,456 B
    float* invn = (float*)(base + 18874368);      //     16,384 B
    float* marg = (float*)(base + 18890752);      //     32,768 B
    int*   cnt  = (int*)(base + 18923520);        //     32,768 B
    u64*   cand = (u64*)(base + 18956288);        //  4,194,304 B -> ends 23,150,592
    int*   bestk = (int*)d_ws;                    // 32 KB (survives into gather)

    hipMemsetAsync(cnt, 0, NQ * sizeof(int), stream);
    prep<<<(NQ + NK) / 4, 256, 0, stream>>>(x_querry, e_k, Xh, Eh, marg, invn);
    gemm256<<<dim3(NQ / 256, NK / 256), 512, 0, stream>>>(Xh, Eh, invn, marg, cnt, cand);
    resolve<<<NQ / 4, 256, 0, stream>>>(cnt, cand, marg, invn, x_querry, e_k, bestk);
    gather_flat<<<2048, 256, 0, stream>>>(bestk, e_p, x_block, (f32x4*)d_out);
}